// Round 9
// baseline (227.180 us; speedup 1.0000x reference)
//
#include <hip/hip_runtime.h>
#include <cstdint>
#include <math.h>

// ---------------------------------------------------------------------------
// Problem constants
//   B=8
//   level 1: fine xyz1 [8,2048,3], coarse xyz2 [8,512,3], x1 [8,256,2048], x2 [8,512,512]
//   level 2: fine xyz0 [8,8192,3], coarse xyz1 [8,2048,3], x0 [8,128,8192]
//   out [8, 896, 8192] f32
// 8-launch schedule:
//   L0 k_prep   : pack coarse xyz + sqnorm into float4 (both levels)
//   L1 k_front  : knn2 | knn1 | copy0 | transB | transA
//                 (knn reads coarse via wave-uniform index -> scalar/broadcast
//                  loads, NO LDS traffic; HBM-bound blocks backfill)
//   L2 k_stats1 (inline merge)   L3 k_finalize -> stats[0:2]
//   L4 k_write1 (inline merge)   -> inter
//   L5 k_stats2 (inline merge)   L6 k_finalize -> stats[2:4]
//   L7 k_write2 (inline merge)   -> out
// NOTE: no __threadfence()/atomics in hot kernels (R7: per-block agent-scope
// fence = buffer_inv storm defeats L2 for concurrent gathers).
// ---------------------------------------------------------------------------

// L0: pack coarse xyz + squared norm. Norm form (x*x+y*y)+z*z matches the
// reference's expanded distance.
__global__ __launch_bounds__(256) void k_prep(const float* __restrict__ xyz1,
                                              const float* __restrict__ xyz2,
                                              float4* __restrict__ c4_2,
                                              float4* __restrict__ c4_1) {
#pragma clang fp contract(off)
    const int i = blockIdx.x * 256 + threadIdx.x;
    const float* src;
    float4* dst;
    if (i < 16384) { src = xyz1 + 3 * (size_t)i; dst = c4_2 + i; }
    else if (i < 20480) { src = xyz2 + 3 * (size_t)(i - 16384); dst = c4_1 + (i - 16384); }
    else return;
    const float x = src[0], y = src[1], z = src[2];
    *dst = make_float4(x, y, z, (x * x + y * y) + z * z);
}

// Merge 6 candidates (2 chunks x sorted top-3, chunk-major => ascending index
// order within equal distances; strict < keeps the earlier candidate, matching
// top_k tie-breaking). Weights = normalized inverse distances.
__device__ __forceinline__ void dev_merge6(const float* __restrict__ cd,
                                           const int* __restrict__ ci,
                                           int& o0, int& o1, int& o2,
                                           float& w0, float& w1, float& w2) {
    float d0 = 1e30f, d1 = 1e30f, d2 = 1e30f;
    int j0 = 0, j1 = 0, j2 = 0;
#pragma unroll
    for (int k = 0; k < 6; ++k) {
        const float d = cd[k];
        const int s = ci[k];
        const bool lt0 = d < d0, lt1 = d < d1, lt2 = d < d2;
        d2 = lt1 ? d1 : (lt2 ? d : d2);
        j2 = lt1 ? j1 : (lt2 ? s : j2);
        d1 = lt0 ? d0 : (lt1 ? d : d1);
        j1 = lt0 ? j0 : (lt1 ? s : j1);
        d0 = lt0 ? d : d0;
        j0 = lt0 ? s : j0;
    }
    const float a = 1.0f / (d0 + 1e-8f);
    const float b = 1.0f / (d1 + 1e-8f);
    const float c = 1.0f / (d2 + 1e-8f);
    const float ws = (a + b) + c;
    o0 = j0; o1 = j1; o2 = j2;
    w0 = a / ws; w1 = b / ws; w2 = c / ws;
}

// kNN chunk scan, LDS-free: coarse read via wave-uniform index from packed
// float4 (scalar/broadcast load). Distance form bit-matches reference:
// fmaf(-2,dot,psq+cw) == (psq+cw) - 2*dot.
template <int CHUNK>
__device__ __forceinline__ void dev_knn_sload(const float* __restrict__ fine,
                                              const float4* __restrict__ coarse4,
                                              int N, int S, int nch,
                                              int b, int nb, int chunk, int tid,
                                              float* __restrict__ cand_d,
                                              int* __restrict__ cand_i) {
#pragma clang fp contract(off)
    const int s0 = chunk * CHUNK;
    const float4* cb = coarse4 + (size_t)b * S + s0;
    const int n = nb * 256 + tid;
    const float* fp = fine + ((size_t)b * N + n) * 3;
    const float px = fp[0], py = fp[1], pz = fp[2];
    const float psq = (px * px + py * py) + pz * pz;
    float d0 = 1e30f, d1 = 1e30f, d2 = 1e30f;
    int i0 = 0, i1 = 0, i2 = 0;
#pragma unroll 4
    for (int s = 0; s < CHUNK; ++s) {
        const float4 c = cb[s];                   // uniform address -> broadcast
        const float dot = (px * c.x + py * c.y) + pz * c.z;
        const float d = fmaf(-2.0f, dot, psq + c.w);
        if (__any(d < d2)) {
            const bool lt0 = d < d0, lt1 = d < d1, lt2 = d < d2;
            d2 = lt1 ? d1 : (lt2 ? d : d2);
            i2 = lt1 ? i1 : (lt2 ? s : i2);
            d1 = lt0 ? d0 : (lt1 ? d : d1);
            i1 = lt0 ? i0 : (lt1 ? s : i1);
            d0 = lt0 ? d : d0;
            i0 = lt0 ? s : i0;
        }
    }
    const size_t p = (((size_t)b * N + n) * nch + chunk) * 3;
    cand_d[p] = d0; cand_d[p + 1] = d1; cand_d[p + 2] = d2;
    cand_i[p] = s0 + i0; cand_i[p + 1] = s0 + i1; cand_i[p + 2] = s0 + i2;
}

__device__ __forceinline__ void dev_transpose(const float* __restrict__ in,
                                              float* __restrict__ out,
                                              int C, long in_bs, long out_bs, int out_rs,
                                              int b, int rt, int ct, int tid,
                                              float* __restrict__ tile /*[32][33]*/) {
    const int r0 = rt * 32, c0 = ct * 32;
    const float* inb = in + (size_t)b * in_bs;
    float* outb = out + (size_t)b * out_bs;
    const int tx = tid & 31, ty = tid >> 5;   // 32 x 8
#pragma unroll
    for (int i = 0; i < 32; i += 8) {
        tile[(ty + i) * 33 + tx] = inb[(size_t)(r0 + ty + i) * C + (c0 + tx)];
    }
    __syncthreads();
#pragma unroll
    for (int i = 0; i < 32; i += 8) {
        outb[(size_t)(c0 + ty + i) * out_rs + (r0 + tx)] = tile[tx * 33 + (ty + i)];
    }
}

// L1: fused front. Blocks:
//   [0,512)        knn level 2 (CHUNK=1024, nch=2): b=id>>6, nb=id&31, chunk=(id>>5)&1
//   [512,640)      knn level 1 (CHUNK=256,  nch=2): t=id-512: b=t>>4, nb=t&7, chunk=(t>>3)&1
//   [640,8832)     copy0  x0 -> out[:,0:128,:]
//   [8832,12928)   transB x1 [8,256,2048] -> inter[b][c][r] (rs=768)
//   [12928,14976)  transA x2 [8,512,512]  -> pts1 (rs=512)
// knn blocks first: they are the VALU pole; HBM-bound blocks backfill.
__global__ __launch_bounds__(256) void k_front(const float* __restrict__ xyz0,
                                               const float* __restrict__ xyz1,
                                               const float4* __restrict__ c4_2,
                                               const float4* __restrict__ c4_1,
                                               const float* __restrict__ x0,
                                               const float* __restrict__ x1,
                                               const float* __restrict__ x2,
                                               float* __restrict__ pts1,
                                               float* __restrict__ inter,
                                               float* __restrict__ out,
                                               float* __restrict__ cand_d2,
                                               int* __restrict__ cand_i2,
                                               float* __restrict__ cand_d1,
                                               int* __restrict__ cand_i1) {
    __shared__ float tile[32 * 33];
    const int id = blockIdx.x;
    const int tid = threadIdx.x;
    if (id < 512) {
        dev_knn_sload<1024>(xyz0, c4_2, 8192, 2048, 2,
                            id >> 6, id & 31, (id >> 5) & 1, tid, cand_d2, cand_i2);
    } else if (id < 640) {
        const int t = id - 512;
        dev_knn_sload<256>(xyz1, c4_1, 2048, 512, 2,
                           t >> 4, t & 7, (t >> 3) & 1, tid, cand_d1, cand_i1);
    } else if (id < 8832) {                      // copy0
        const size_t i = (size_t)(id - 640) * 256 + tid;
        const size_t b = i >> 18;
        const size_t off = i & (((size_t)1 << 18) - 1);
        const float4* src = (const float4*)(x0 + b * (size_t)128 * 8192);
        float4* dst = (float4*)(out + b * (size_t)896 * 8192);
        dst[off] = src[off];
    } else if (id < 12928) {                     // transB
        const int t = id - 8832;
        const int ct = t & 63, rt = (t >> 6) & 7, b = t >> 9;
        dev_transpose(x1, inter, 2048, 256 * 2048, (long)2048 * 768, 768,
                      b, rt, ct, tid, tile);
    } else {                                     // transA
        const int t = id - 12928;
        const int ct = t & 15, rt = (t >> 4) & 15, b = t >> 8;
        dev_transpose(x2, pts1, 512, 512 * 512, 512 * 512, 512,
                      b, rt, ct, tid, tile);
    }
}

// Stats gather pass with inline merge; writes per-block double partials only.
// Grid (x=B, y=N/32, z=C/256); blockIdx.x = batch -> XCD-pinned L2 reuse.
__global__ __launch_bounds__(256) void k_interp_stats(const float* __restrict__ pts,
                                                      const float* __restrict__ cand_d,
                                                      const int* __restrict__ cand_i,
                                                      int N, int S, int C,
                                                      double* __restrict__ partials) {
    __shared__ int   si[32][3];
    __shared__ float sw[32][3];
    const int b = blockIdx.x, nb = blockIdx.y, cb = blockIdx.z;
    const int n0 = nb * 32;
    const int tid = threadIdx.x;
    if (tid < 32) {
        const size_t pt = (size_t)b * N + n0 + tid;
        dev_merge6(cand_d + pt * 6, cand_i + pt * 6,
                   si[tid][0], si[tid][1], si[tid][2],
                   sw[tid][0], sw[tid][1], sw[tid][2]);
    }
    __syncthreads();
    const int C4 = C >> 2;
    const float4* pbf = (const float4*)(pts + (size_t)b * S * C) + (cb * 64);
    const int f = tid & 63;
    const int pg = tid >> 6;
    double ls = 0.0, lq = 0.0;
#pragma unroll
    for (int g = 0; g < 8; ++g) {
        const int nl = g * 4 + pg;
        const size_t r0 = (size_t)si[nl][0] * C4;
        const size_t r1 = (size_t)si[nl][1] * C4;
        const size_t r2 = (size_t)si[nl][2] * C4;
        const float w0 = sw[nl][0], w1 = sw[nl][1], w2 = sw[nl][2];
        const float4 a = pbf[r0 + f], c = pbf[r1 + f], e = pbf[r2 + f];
        const float vx = (w0 * a.x + w1 * c.x) + w2 * e.x;
        const float vy = (w0 * a.y + w1 * c.y) + w2 * e.y;
        const float vz = (w0 * a.z + w1 * c.z) + w2 * e.z;
        const float vw = (w0 * a.w + w1 * c.w) + w2 * e.w;
        ls += (double)vx + (double)vy + (double)vz + (double)vw;
        lq += (double)vx * vx + (double)vy * vy + (double)vz * vz + (double)vw * vw;
    }
    __shared__ double sa[256], sb[256];
    sa[tid] = ls; sb[tid] = lq; __syncthreads();
    for (int s = 128; s > 0; s >>= 1) {
        if (tid < s) { sa[tid] += sa[tid + s]; sb[tid] += sb[tid + s]; }
        __syncthreads();
    }
    if (tid == 0) {
        const size_t pl = ((size_t)cb * gridDim.x + b) * gridDim.y + nb;
        partials[2 * pl] = sa[0]; partials[2 * pl + 1] = sb[0];
    }
}

// Deterministic single-block reduction of partials -> {mean, 1/(std+1e-5)}.
__global__ __launch_bounds__(1024) void k_finalize(const double* __restrict__ partials,
                                                   int P, double nelem,
                                                   float* __restrict__ stats) {
    __shared__ double sa[1024], sb[1024];
    double ls = 0.0, lq = 0.0;
    for (int i = threadIdx.x; i < P; i += 1024) { ls += partials[2 * i]; lq += partials[2 * i + 1]; }
    const int t = threadIdx.x;
    sa[t] = ls; sb[t] = lq; __syncthreads();
    for (int s = 512; s > 0; s >>= 1) {
        if (t < s) { sa[t] += sa[t + s]; sb[t] += sb[t + s]; }
        __syncthreads();
    }
    if (t == 0) {
        const double sum = sa[0], sq = sb[0];
        const double m = sum / nelem;
        const double var = (sq - sum * sum / nelem) / (nelem - 1.0);
        const double sd = sqrt(var > 0.0 ? var : 0.0);
        stats[0] = (float)m;
        stats[1] = (float)(1.0 / (sd + 1e-5));
    }
}

// Level-1 write pass, float4: grid (x=B, y=N/4). One wave per fine point;
// the wave redundantly merges its point's 6 candidates (uniform loads).
__global__ __launch_bounds__(256) void k_interp1_write(const float* __restrict__ pts,
                                                       const float* __restrict__ cand_d,
                                                       const int* __restrict__ cand_i,
                                                       const float* __restrict__ stats,
                                                       float* __restrict__ inter) {
    const float m = stats[0], rs = stats[1];
    const int b = blockIdx.x;
    const int n0 = blockIdx.y * 4;
    const int tid = threadIdx.x;
    const int pt = tid >> 6, f = tid & 63;
    const size_t p = (size_t)b * 2048 + n0 + pt;
    int i0, i1, i2; float w0, w1, w2;
    dev_merge6(cand_d + p * 6, cand_i + p * 6, i0, i1, i2, w0, w1, w2);
    const float4* pb4 = (const float4*)(pts + (size_t)b * 512 * 512);
    const size_t r0 = (size_t)i0 * 128, r1 = (size_t)i1 * 128, r2 = (size_t)i2 * 128;
    float4* out4 = (float4*)(inter + p * 768 + 256);
#pragma unroll
    for (int k = 0; k < 2; ++k) {
        const int c = f + k * 64;
        const float4 a = pb4[r0 + c], d = pb4[r1 + c], e = pb4[r2 + c];
        float4 v;
        v.x = (((w0 * a.x + w1 * d.x) + w2 * e.x) - m) * rs;
        v.y = (((w0 * a.y + w1 * d.y) + w2 * e.y) - m) * rs;
        v.z = (((w0 * a.z + w1 * d.z) + w2 * e.z) - m) * rs;
        v.w = (((w0 * a.w + w1 * d.w) + w2 * e.w) - m) * rs;
        out4[c] = v;
    }
}

// Level-2 write pass: grid (x=B, y=128 n-tiles, z=12 c-blocks). Gather rows of
// inter [8,2048,768], normalize, write TRANSPOSED into out via 64x64 LDS tile.
__global__ __launch_bounds__(256) void k_interp2_write(const float* __restrict__ pts,
                                                       const float* __restrict__ cand_d,
                                                       const int* __restrict__ cand_i,
                                                       const float* __restrict__ stats,
                                                       float* __restrict__ out) {
    __shared__ float tile[64][65];
    __shared__ int   si[64][3];
    __shared__ float sw[64][3];
    const float m = stats[0], rs = stats[1];
    const int b = blockIdx.x, nt = blockIdx.y, cc = blockIdx.z;
    const int n0 = nt * 64, c0 = cc * 64;
    const int tid = threadIdx.x;
    if (tid < 64) {
        const size_t pt = (size_t)b * 8192 + n0 + tid;
        dev_merge6(cand_d + pt * 6, cand_i + pt * 6,
                   si[tid][0], si[tid][1], si[tid][2],
                   sw[tid][0], sw[tid][1], sw[tid][2]);
    }
    __syncthreads();
    const float* pb = pts + (size_t)b * 2048 * 768 + c0;
    const int cl = tid & 63;
    const int pg = tid >> 6;
#pragma unroll
    for (int pass = 0; pass < 16; ++pass) {
        const int nl = pass * 4 + pg;
        const float v = (sw[nl][0] * pb[(size_t)si[nl][0] * 768 + cl]
                       + sw[nl][1] * pb[(size_t)si[nl][1] * 768 + cl])
                       + sw[nl][2] * pb[(size_t)si[nl][2] * 768 + cl];
        tile[nl][cl] = (v - m) * rs;
    }
    __syncthreads();
    float* ob = out + (size_t)b * 896 * 8192 + (size_t)(128 + c0) * 8192 + n0;
    const int tn = tid & 63, tc0 = tid >> 6;
#pragma unroll
    for (int pass = 0; pass < 16; ++pass) {
        const int tc = pass * 4 + tc0;
        ob[(size_t)tc * 8192 + tn] = tile[tn][tc];
    }
}

extern "C" void kernel_launch(void* const* d_in, const int* in_sizes, int n_in,
                              void* d_out, int out_size, void* d_ws, size_t ws_size,
                              hipStream_t stream) {
    const float* xyz0 = (const float*)d_in[0];
    const float* xyz1 = (const float*)d_in[1];
    const float* xyz2 = (const float*)d_in[2];
    const float* x0   = (const float*)d_in[3];
    const float* x1   = (const float*)d_in[4];
    const float* x2   = (const float*)d_in[5];
    float* out = (float*)d_out;
    char* ws = (char*)d_ws;

    size_t off = 0;
    auto alloc = [&](size_t bytes) {
        size_t o = off;
        off = (off + bytes + 255) & ~(size_t)255;
        return o;
    };
    float*  stats    = (float*)(ws + alloc(8 * sizeof(float)));
    double* partials = (double*)(ws + alloc((size_t)6144 * 2 * sizeof(double)));
    float4* c4_2     = (float4*)(ws + alloc((size_t)16384 * 16));         // xyz1 packed
    float4* c4_1     = (float4*)(ws + alloc((size_t)4096 * 16));          // xyz2 packed
    float*  pts1     = (float*)(ws + alloc((size_t)8 * 512 * 512 * 4));   // x2^T
    float*  inter    = (float*)(ws + alloc((size_t)8 * 2048 * 768 * 4));  // [8,2048,768]
    float*  cand_d2  = (float*)(ws + alloc((size_t)65536 * 6 * 4));
    int*    cand_i2  = (int*)(ws + alloc((size_t)65536 * 6 * 4));
    float*  cand_d1  = (float*)(ws + alloc((size_t)16384 * 6 * 4));
    int*    cand_i1  = (int*)(ws + alloc((size_t)16384 * 6 * 4));

    // L0: pack coarse points
    k_prep<<<80, 256, 0, stream>>>(xyz1, xyz2, c4_2, c4_1);
    // L1: knn2 | knn1 | copy0 | transB | transA
    k_front<<<14976, 256, 0, stream>>>(xyz0, xyz1, c4_2, c4_1, x0, x1, x2,
                                       pts1, inter, out,
                                       cand_d2, cand_i2, cand_d1, cand_i1);
    // L2-L4: level 1
    k_interp_stats<<<dim3(8, 64, 2), 256, 0, stream>>>(
        pts1, cand_d1, cand_i1, 2048, 512, 512, partials);
    k_finalize<<<1, 1024, 0, stream>>>(partials, 1024, (double)8 * 2048 * 512, stats);
    k_interp1_write<<<dim3(8, 512), 256, 0, stream>>>(pts1, cand_d1, cand_i1, stats, inter);
    // L5-L7: level 2
    k_interp_stats<<<dim3(8, 256, 3), 256, 0, stream>>>(
        inter, cand_d2, cand_i2, 8192, 2048, 768, partials);
    k_finalize<<<1, 1024, 0, stream>>>(partials, 6144, (double)8 * 8192 * 768, stats + 2);
    k_interp2_write<<<dim3(8, 128, 12), 256, 0, stream>>>(inter, cand_d2, cand_i2,
                                                          stats + 2, out);
}

// Round 10
// 187.821 us; speedup vs baseline: 1.2096x; 1.2096x over previous
//
#include <hip/hip_runtime.h>
#include <cstdint>
#include <math.h>

// ---------------------------------------------------------------------------
// Problem constants
//   B=8
//   level 1: fine xyz1 [8,2048,3], coarse xyz2 [8,512,3], x1 [8,256,2048], x2 [8,512,512]
//   level 2: fine xyz0 [8,8192,3], coarse xyz1 [8,2048,3], x0 [8,128,8192]
//   out [8, 896, 8192] f32
// 5-launch schedule (inter holds RAW level-1 interp; normalization deferred
// into write2 as a per-region affine alpha*v+beta):
//   L1 k_front         : knn2 | knn1 | copy0 | transB | transA  (R8 structure)
//   L2 k_interp1_fused : gather pts1 -> raw inter[:, :, 256:768] + partials1
//   L3 k_interp_stats  : gather raw inter -> partials2 (per-cb region split)
//   L4 k_fin_combined  : double reduce + affine correction -> {a,b}x{lo,hi}
//   L5 k_interp2_write : gather raw inter, out = a*v + b (per c-block a,b)
// Rules learned: no per-block agent-scope fences/atomics in hot kernels (R7);
// LDS-staged knn beats uniform VMEM scan at this occupancy (R9).
// ---------------------------------------------------------------------------

// Merge 6 candidates (2 chunks x sorted top-3, chunk-major => ascending index
// order within equal distances; strict < keeps the earlier candidate, matching
// top_k tie-breaking). Weights = normalized inverse distances.
__device__ __forceinline__ void dev_merge6(const float* __restrict__ cd,
                                           const int* __restrict__ ci,
                                           int& o0, int& o1, int& o2,
                                           float& w0, float& w1, float& w2) {
    float d0 = 1e30f, d1 = 1e30f, d2 = 1e30f;
    int j0 = 0, j1 = 0, j2 = 0;
#pragma unroll
    for (int k = 0; k < 6; ++k) {
        const float d = cd[k];
        const int s = ci[k];
        const bool lt0 = d < d0, lt1 = d < d1, lt2 = d < d2;
        d2 = lt1 ? d1 : (lt2 ? d : d2);
        j2 = lt1 ? j1 : (lt2 ? s : j2);
        d1 = lt0 ? d0 : (lt1 ? d : d1);
        j1 = lt0 ? j0 : (lt1 ? s : j1);
        d0 = lt0 ? d : d0;
        j0 = lt0 ? s : j0;
    }
    const float a = 1.0f / (d0 + 1e-8f);
    const float b = 1.0f / (d1 + 1e-8f);
    const float c = 1.0f / (d2 + 1e-8f);
    const float ws = (a + b) + c;
    o0 = j0; o1 = j1; o2 = j2;
    w0 = a / ws; w1 = b / ws; w2 = c / ws;
}

// kNN chunk scan with inline LDS pack of the coarse chunk.
// Distance form bit-matches reference: fmaf(-2,dot,psq+cw) == (psq+cw)-2*dot.
template <int CHUNK>
__device__ __forceinline__ void dev_knn_lds(const float* __restrict__ fine,
                                            const float* __restrict__ coarse,
                                            int N, int S, int nch,
                                            int b, int nb, int chunk, int tid,
                                            float4* __restrict__ lc,
                                            float* __restrict__ cand_d,
                                            int* __restrict__ cand_i) {
#pragma clang fp contract(off)
    const int s0 = chunk * CHUNK;
    const float* cb = coarse + ((size_t)b * S + s0) * 3;
    for (int s = tid; s < CHUNK; s += 256) {
        const float x = cb[3 * s], y = cb[3 * s + 1], z = cb[3 * s + 2];
        lc[s] = make_float4(x, y, z, (x * x + y * y) + z * z);
    }
    __syncthreads();
    const int n = nb * 256 + tid;
    const float* fp = fine + ((size_t)b * N + n) * 3;
    const float px = fp[0], py = fp[1], pz = fp[2];
    const float psq = (px * px + py * py) + pz * pz;
    float d0 = 1e30f, d1 = 1e30f, d2 = 1e30f;
    int i0 = 0, i1 = 0, i2 = 0;
#pragma unroll 4
    for (int s = 0; s < CHUNK; ++s) {
        const float4 c = lc[s];
        const float dot = (px * c.x + py * c.y) + pz * c.z;
        const float d = fmaf(-2.0f, dot, psq + c.w);
        if (__any(d < d2)) {
            const bool lt0 = d < d0, lt1 = d < d1, lt2 = d < d2;
            d2 = lt1 ? d1 : (lt2 ? d : d2);
            i2 = lt1 ? i1 : (lt2 ? s : i2);
            d1 = lt0 ? d0 : (lt1 ? d : d1);
            i1 = lt0 ? i0 : (lt1 ? s : i1);
            d0 = lt0 ? d : d0;
            i0 = lt0 ? s : i0;
        }
    }
    const size_t p = (((size_t)b * N + n) * nch + chunk) * 3;
    cand_d[p] = d0; cand_d[p + 1] = d1; cand_d[p + 2] = d2;
    cand_i[p] = s0 + i0; cand_i[p + 1] = s0 + i1; cand_i[p + 2] = s0 + i2;
}

__device__ __forceinline__ void dev_transpose(const float* __restrict__ in,
                                              float* __restrict__ out,
                                              int C, long in_bs, long out_bs, int out_rs,
                                              int b, int rt, int ct, int tid,
                                              float* __restrict__ tile /*[32][33]*/) {
    const int r0 = rt * 32, c0 = ct * 32;
    const float* inb = in + (size_t)b * in_bs;
    float* outb = out + (size_t)b * out_bs;
    const int tx = tid & 31, ty = tid >> 5;   // 32 x 8
#pragma unroll
    for (int i = 0; i < 32; i += 8) {
        tile[(ty + i) * 33 + tx] = inb[(size_t)(r0 + ty + i) * C + (c0 + tx)];
    }
    __syncthreads();
#pragma unroll
    for (int i = 0; i < 32; i += 8) {
        outb[(size_t)(c0 + ty + i) * out_rs + (r0 + tx)] = tile[tx * 33 + (ty + i)];
    }
}

// L1: fused front (identical to R8). Blocks:
//   [0,512)        knn level 2 (CHUNK=1024, nch=2): b=id>>6, nb=id&31, chunk=(id>>5)&1
//   [512,640)      knn level 1 (CHUNK=256,  nch=2): t=id-512: b=t>>4, nb=t&7, chunk=(t>>3)&1
//   [640,8832)     copy0  x0 -> out[:,0:128,:]
//   [8832,12928)   transB x1 [8,256,2048] -> inter[b][c][r] (rs=768)
//   [12928,14976)  transA x2 [8,512,512]  -> pts1 (rs=512)
__global__ __launch_bounds__(256) void k_front(const float* __restrict__ xyz0,
                                               const float* __restrict__ xyz1,
                                               const float* __restrict__ xyz2,
                                               const float* __restrict__ x0,
                                               const float* __restrict__ x1,
                                               const float* __restrict__ x2,
                                               float* __restrict__ pts1,
                                               float* __restrict__ inter,
                                               float* __restrict__ out,
                                               float* __restrict__ cand_d2,
                                               int* __restrict__ cand_i2,
                                               float* __restrict__ cand_d1,
                                               int* __restrict__ cand_i1) {
    __shared__ __align__(16) char smem[16384];   // union: lc (16K) | tile (4.2K)
    const int id = blockIdx.x;
    const int tid = threadIdx.x;
    if (id < 512) {
        dev_knn_lds<1024>(xyz0, xyz1, 8192, 2048, 2,
                          id >> 6, id & 31, (id >> 5) & 1, tid,
                          (float4*)smem, cand_d2, cand_i2);
    } else if (id < 640) {
        const int t = id - 512;
        dev_knn_lds<256>(xyz1, xyz2, 2048, 512, 2,
                         t >> 4, t & 7, (t >> 3) & 1, tid,
                         (float4*)smem, cand_d1, cand_i1);
    } else if (id < 8832) {                      // copy0
        const size_t i = (size_t)(id - 640) * 256 + tid;
        const size_t b = i >> 18;
        const size_t off = i & (((size_t)1 << 18) - 1);
        const float4* src = (const float4*)(x0 + b * (size_t)128 * 8192);
        float4* dst = (float4*)(out + b * (size_t)896 * 8192);
        dst[off] = src[off];
    } else if (id < 12928) {                     // transB
        const int t = id - 8832;
        const int ct = t & 63, rt = (t >> 6) & 7, b = t >> 9;
        dev_transpose(x1, inter, 2048, 256 * 2048, (long)2048 * 768, 768,
                      b, rt, ct, tid, (float*)smem);
    } else {                                     // transA
        const int t = id - 12928;
        const int ct = t & 15, rt = (t >> 4) & 15, b = t >> 8;
        dev_transpose(x2, pts1, 512, 512 * 512, 512 * 512, 512,
                      b, rt, ct, tid, (float*)smem);
    }
}

// L2: level-1 fused gather: write RAW interp to inter[:, :, 256:768] and
// accumulate double partials. Grid (x=8, y=128); 16 points/block; one wave
// per point-slot (4 waves x 4 loop rounds), float4 gathers from L2-resident
// pts1. Raw value form identical to previous rounds: (w0*a + w1*d) + w2*e.
__global__ __launch_bounds__(256) void k_interp1_fused(const float* __restrict__ pts,
                                                       const float* __restrict__ cand_d,
                                                       const int* __restrict__ cand_i,
                                                       float* __restrict__ inter,
                                                       double* __restrict__ partials1) {
    __shared__ int   si[16][3];
    __shared__ float sw[16][3];
    const int b = blockIdx.x, nb = blockIdx.y;
    const int n0 = nb * 16;
    const int tid = threadIdx.x;
    if (tid < 16) {
        const size_t pt = (size_t)b * 2048 + n0 + tid;
        dev_merge6(cand_d + pt * 6, cand_i + pt * 6,
                   si[tid][0], si[tid][1], si[tid][2],
                   sw[tid][0], sw[tid][1], sw[tid][2]);
    }
    __syncthreads();
    const float4* pb4 = (const float4*)(pts + (size_t)b * 512 * 512);
    const int pg = tid >> 6, f = tid & 63;
    double ls = 0.0, lq = 0.0;
#pragma unroll
    for (int g = 0; g < 4; ++g) {
        const int pl = g * 4 + pg;
        const size_t p = (size_t)b * 2048 + n0 + pl;
        const size_t r0 = (size_t)si[pl][0] * 128;
        const size_t r1 = (size_t)si[pl][1] * 128;
        const size_t r2 = (size_t)si[pl][2] * 128;
        const float w0 = sw[pl][0], w1 = sw[pl][1], w2 = sw[pl][2];
        float4* out4 = (float4*)(inter + p * 768 + 256);
#pragma unroll
        for (int k = 0; k < 2; ++k) {
            const int c = f + k * 64;
            const float4 a = pb4[r0 + c], d = pb4[r1 + c], e = pb4[r2 + c];
            float4 v;
            v.x = (w0 * a.x + w1 * d.x) + w2 * e.x;
            v.y = (w0 * a.y + w1 * d.y) + w2 * e.y;
            v.z = (w0 * a.z + w1 * d.z) + w2 * e.z;
            v.w = (w0 * a.w + w1 * d.w) + w2 * e.w;
            out4[c] = v;
            ls += (double)v.x + (double)v.y + (double)v.z + (double)v.w;
            lq += (double)v.x * v.x + (double)v.y * v.y
                + (double)v.z * v.z + (double)v.w * v.w;
        }
    }
    __shared__ double sa[256], sb[256];
    sa[tid] = ls; sb[tid] = lq; __syncthreads();
    for (int s = 128; s > 0; s >>= 1) {
        if (tid < s) { sa[tid] += sa[tid + s]; sb[tid] += sb[tid + s]; }
        __syncthreads();
    }
    if (tid == 0) {
        const size_t pl = (size_t)b * gridDim.y + nb;
        partials1[2 * pl] = sa[0]; partials1[2 * pl + 1] = sb[0];
    }
}

// L3: stats gather over raw inter; per-block double partials, cb-major layout
// so the finalize can split c<256 (cb=0) from c>=256 (cb=1,2).
// Grid (x=B, y=N/32, z=C/256); blockIdx.x = batch -> XCD-pinned L2 reuse.
__global__ __launch_bounds__(256) void k_interp_stats(const float* __restrict__ pts,
                                                      const float* __restrict__ cand_d,
                                                      const int* __restrict__ cand_i,
                                                      int N, int S, int C,
                                                      double* __restrict__ partials) {
    __shared__ int   si[32][3];
    __shared__ float sw[32][3];
    const int b = blockIdx.x, nb = blockIdx.y, cb = blockIdx.z;
    const int n0 = nb * 32;
    const int tid = threadIdx.x;
    if (tid < 32) {
        const size_t pt = (size_t)b * N + n0 + tid;
        dev_merge6(cand_d + pt * 6, cand_i + pt * 6,
                   si[tid][0], si[tid][1], si[tid][2],
                   sw[tid][0], sw[tid][1], sw[tid][2]);
    }
    __syncthreads();
    const int C4 = C >> 2;
    const float4* pbf = (const float4*)(pts + (size_t)b * S * C) + (cb * 64);
    const int f = tid & 63;
    const int pg = tid >> 6;
    double ls = 0.0, lq = 0.0;
#pragma unroll
    for (int g = 0; g < 8; ++g) {
        const int nl = g * 4 + pg;
        const size_t r0 = (size_t)si[nl][0] * C4;
        const size_t r1 = (size_t)si[nl][1] * C4;
        const size_t r2 = (size_t)si[nl][2] * C4;
        const float w0 = sw[nl][0], w1 = sw[nl][1], w2 = sw[nl][2];
        const float4 a = pbf[r0 + f], c = pbf[r1 + f], e = pbf[r2 + f];
        const float vx = (w0 * a.x + w1 * c.x) + w2 * e.x;
        const float vy = (w0 * a.y + w1 * c.y) + w2 * e.y;
        const float vz = (w0 * a.z + w1 * c.z) + w2 * e.z;
        const float vw = (w0 * a.w + w1 * c.w) + w2 * e.w;
        ls += (double)vx + (double)vy + (double)vz + (double)vw;
        lq += (double)vx * vx + (double)vy * vy + (double)vz * vz + (double)vw * vw;
    }
    __shared__ double sa[256], sb[256];
    sa[tid] = ls; sb[tid] = lq; __syncthreads();
    for (int s = 128; s > 0; s >>= 1) {
        if (tid < s) { sa[tid] += sa[tid + s]; sb[tid] += sb[tid + s]; }
        __syncthreads();
    }
    if (tid == 0) {
        const size_t pl = ((size_t)cb * gridDim.x + b) * gridDim.y + nb;
        partials[2 * pl] = sa[0]; partials[2 * pl + 1] = sb[0];
    }
}

// L4: combined finalize (1 block). Level-1 stats from partials1; level-2 stats
// from raw partials2 with affine correction (inter holds RAW interp for
// c>=256; final values would be a1*raw + b1 with a1=rs1, b1=-m1*rs1).
// Emits stats4 = {alpha_lo, beta_lo, alpha_hi, beta_hi} for write2:
//   out = alpha*v_raw + beta  ==  (v_final - m2) * rs2.
__global__ __launch_bounds__(256) void k_fin_combined(const double* __restrict__ partials1,
                                                      int P1,
                                                      const double* __restrict__ partials2,
                                                      int P2, int P2lo,
                                                      float* __restrict__ stats4) {
    __shared__ double red[6][256];
    const int t = threadIdx.x;
    double s1 = 0.0, q1 = 0.0, s2l = 0.0, q2l = 0.0, s2h = 0.0, q2h = 0.0;
    for (int i = t; i < P1; i += 256) { s1 += partials1[2 * i]; q1 += partials1[2 * i + 1]; }
    for (int i = t; i < P2; i += 256) {
        const double s = partials2[2 * i], q = partials2[2 * i + 1];
        if (i < P2lo) { s2l += s; q2l += q; } else { s2h += s; q2h += q; }
    }
    red[0][t] = s1; red[1][t] = q1; red[2][t] = s2l;
    red[3][t] = q2l; red[4][t] = s2h; red[5][t] = q2h;
    __syncthreads();
    for (int s = 128; s > 0; s >>= 1) {
        if (t < s) {
#pragma unroll
            for (int r = 0; r < 6; ++r) red[r][t] += red[r][t + s];
        }
        __syncthreads();
    }
    if (t == 0) {
        const double nelem1 = 8388608.0;      // 8*2048*512
        const double cnt2   = 50331648.0;     // 8*8192*768
        const double cnthi  = 33554432.0;     // 8*8192*512
        const double S1 = red[0][0], Q1 = red[1][0];
        const double m1 = S1 / nelem1;
        const double v1 = (Q1 - S1 * S1 / nelem1) / (nelem1 - 1.0);
        const double sd1 = sqrt(v1 > 0.0 ? v1 : 0.0);
        const float rs1f = (float)(1.0 / (sd1 + 1e-5));
        const float m1f = (float)m1;
        const double a1 = (double)rs1f;
        const double b1 = -(double)m1f * (double)rs1f;
        const double S2l = red[2][0], Q2l = red[3][0];
        const double S2h = red[4][0], Q2h = red[5][0];
        const double Sf = S2l + a1 * S2h + b1 * cnthi;
        const double Qf = Q2l + a1 * a1 * Q2h + 2.0 * a1 * b1 * S2h + b1 * b1 * cnthi;
        const double m2 = Sf / cnt2;
        const double v2 = (Qf - Sf * Sf / cnt2) / (cnt2 - 1.0);
        const double sd2 = sqrt(v2 > 0.0 ? v2 : 0.0);
        const double rs2 = 1.0 / (sd2 + 1e-5);
        stats4[0] = (float)rs2;                 // alpha_lo (c < 256)
        stats4[1] = (float)(-m2 * rs2);         // beta_lo
        stats4[2] = (float)(a1 * rs2);          // alpha_hi (c >= 256)
        stats4[3] = (float)((b1 - m2) * rs2);   // beta_hi
    }
}

// L5: level-2 write pass: grid (x=B, y=128 n-tiles, z=12 c-blocks). Gather raw
// inter rows, apply per-region affine, write TRANSPOSED via 64x64 LDS tile.
__global__ __launch_bounds__(256) void k_interp2_write(const float* __restrict__ pts,
                                                       const float* __restrict__ cand_d,
                                                       const int* __restrict__ cand_i,
                                                       const float* __restrict__ stats4,
                                                       float* __restrict__ out) {
    __shared__ float tile[64][65];
    __shared__ int   si[64][3];
    __shared__ float sw[64][3];
    const int b = blockIdx.x, nt = blockIdx.y, cc = blockIdx.z;
    const float alpha = (cc < 4) ? stats4[0] : stats4[2];
    const float beta  = (cc < 4) ? stats4[1] : stats4[3];
    const int n0 = nt * 64, c0 = cc * 64;
    const int tid = threadIdx.x;
    if (tid < 64) {
        const size_t pt = (size_t)b * 8192 + n0 + tid;
        dev_merge6(cand_d + pt * 6, cand_i + pt * 6,
                   si[tid][0], si[tid][1], si[tid][2],
                   sw[tid][0], sw[tid][1], sw[tid][2]);
    }
    __syncthreads();
    const float* pb = pts + (size_t)b * 2048 * 768 + c0;
    const int cl = tid & 63;
    const int pg = tid >> 6;
#pragma unroll
    for (int pass = 0; pass < 16; ++pass) {
        const int nl = pass * 4 + pg;
        const float v = (sw[nl][0] * pb[(size_t)si[nl][0] * 768 + cl]
                       + sw[nl][1] * pb[(size_t)si[nl][1] * 768 + cl])
                       + sw[nl][2] * pb[(size_t)si[nl][2] * 768 + cl];
        tile[nl][cl] = alpha * v + beta;
    }
    __syncthreads();
    float* ob = out + (size_t)b * 896 * 8192 + (size_t)(128 + c0) * 8192 + n0;
    const int tn = tid & 63, tc0 = tid >> 6;
#pragma unroll
    for (int pass = 0; pass < 16; ++pass) {
        const int tc = pass * 4 + tc0;
        ob[(size_t)tc * 8192 + tn] = tile[tn][tc];
    }
}

extern "C" void kernel_launch(void* const* d_in, const int* in_sizes, int n_in,
                              void* d_out, int out_size, void* d_ws, size_t ws_size,
                              hipStream_t stream) {
    const float* xyz0 = (const float*)d_in[0];
    const float* xyz1 = (const float*)d_in[1];
    const float* xyz2 = (const float*)d_in[2];
    const float* x0   = (const float*)d_in[3];
    const float* x1   = (const float*)d_in[4];
    const float* x2   = (const float*)d_in[5];
    float* out = (float*)d_out;
    char* ws = (char*)d_ws;

    size_t off = 0;
    auto alloc = [&](size_t bytes) {
        size_t o = off;
        off = (off + bytes + 255) & ~(size_t)255;
        return o;
    };
    float*  stats4    = (float*)(ws + alloc(4 * sizeof(float)));
    double* partials1 = (double*)(ws + alloc((size_t)1024 * 2 * sizeof(double)));
    double* partials2 = (double*)(ws + alloc((size_t)6144 * 2 * sizeof(double)));
    float*  pts1      = (float*)(ws + alloc((size_t)8 * 512 * 512 * 4));   // x2^T
    float*  inter     = (float*)(ws + alloc((size_t)8 * 2048 * 768 * 4));  // RAW [8,2048,768]
    float*  cand_d2   = (float*)(ws + alloc((size_t)65536 * 6 * 4));
    int*    cand_i2   = (int*)(ws + alloc((size_t)65536 * 6 * 4));
    float*  cand_d1   = (float*)(ws + alloc((size_t)16384 * 6 * 4));
    int*    cand_i1   = (int*)(ws + alloc((size_t)16384 * 6 * 4));

    // L1: knn2 | knn1 | copy0 | transB | transA
    k_front<<<14976, 256, 0, stream>>>(xyz0, xyz1, xyz2, x0, x1, x2,
                                       pts1, inter, out,
                                       cand_d2, cand_i2, cand_d1, cand_i1);
    // L2: level-1 fused raw write + partials1
    k_interp1_fused<<<dim3(8, 128), 256, 0, stream>>>(
        pts1, cand_d1, cand_i1, inter, partials1);
    // L3: level-2 raw stats -> partials2 (cb-major: first 2048 = c<256)
    k_interp_stats<<<dim3(8, 256, 3), 256, 0, stream>>>(
        inter, cand_d2, cand_i2, 8192, 2048, 768, partials2);
    // L4: combined finalize -> stats4
    k_fin_combined<<<1, 256, 0, stream>>>(partials1, 1024, partials2, 6144, 2048, stats4);
    // L5: level-2 write with per-region affine
    k_interp2_write<<<dim3(8, 128, 12), 256, 0, stream>>>(inter, cand_d2, cand_i2,
                                                          stats4, out);
}